// Round 7
// baseline (560.180 us; speedup 1.0000x reference)
//
#include <hip/hip_runtime.h>
#include <math.h>

#define T_STEPS 16
#define DIM_X 64
#define DIM_H 128
#define DIM_K 192
#define NPACK 512        // packed gate rows = 4*DIM_H
#define MSEQ 64          // sequences per chunk
#define NTHREADS 512     // 8 waves
#define LDK 200          // padded LDS row length in ushorts (400B, 16B-aligned)
#define PREP_THREADS 256
#define PACK_ITEMS (NPACK * DIM_K)                 // 98304
#define PACK_BLOCKS (PACK_ITEMS / PREP_THREADS)    // 384

typedef __attribute__((ext_vector_type(8))) short bf16x8;
typedef __attribute__((ext_vector_type(4))) float f32x4;

__device__ __forceinline__ float fsigmoid(float x) {
    return 1.0f / (1.0f + __expf(-x));
}
__device__ __forceinline__ float ftanh_(float x) {
    float a = fabsf(x);
    float e = __expf(2.0f * a);
    float r = 1.0f - 2.0f / (e + 1.0f);   // safe at e=inf -> r=1
    return copysignf(r, x);
}
__device__ __forceinline__ unsigned short bf16_rn(float x) {
    unsigned int b = __float_as_uint(x);
    b += 0x7FFFu + ((b >> 16) & 1u);
    return (unsigned short)(b >> 16);
}
__device__ __forceinline__ float bf16_to_f(unsigned short u) {
    return __uint_as_float(((unsigned int)u) << 16);
}

// Fused prepass. Blocks [0, PACK_BLOCKS): pack W into gate-major bf16 hi/lo.
// Block PACK_BLOCKS: histogram lengths, DESC scan, scatter seq ids into list
// (longest bins first), and reset the steal counter.
__global__ __launch_bounds__(PREP_THREADS)
void prep(const float* __restrict__ W_ih, const float* __restrict__ W_hh,
          const float* __restrict__ b_ih, const float* __restrict__ b_hh,
          const int* __restrict__ xn, int N,
          unsigned short* __restrict__ Whi, unsigned short* __restrict__ Wlo,
          float* __restrict__ bsum, int* __restrict__ list, int* __restrict__ ctr) {
    const int b = blockIdx.x;
    const int tid = threadIdx.x;
    if (b < PACK_BLOCKS) {
        int i = b * PREP_THREADS + tid;
        int p = i / DIM_K, k = i % DIM_K;
        int g = (p >> 4) & 3;
        int unit = ((p >> 6) << 4) + (p & 15);
        int r = g * DIM_H + unit;
        float v = (k < DIM_X) ? W_ih[r * DIM_X + k] : W_hh[r * DIM_H + (k - DIM_X)];
        unsigned short hi = bf16_rn(v);
        Whi[i] = hi;
        Wlo[i] = bf16_rn(v - bf16_to_f(hi));
        if (k == 0) bsum[p] = b_ih[r] + b_hh[r];
        return;
    }
    // binning block
    __shared__ int hist[T_STEPS], offs[T_STEPS], cur[T_STEPS];
    if (tid < T_STEPS) hist[tid] = 0;
    if (tid == 0) *ctr = 0;
    __syncthreads();
    for (int i = tid; i < N; i += PREP_THREADS) {
        int len = xn[i * 4 + 3];
        len = min(max(len, 1), T_STEPS);
        atomicAdd(&hist[len - 1], 1);
    }
    __syncthreads();
    if (tid == 0) {
        int acc = 0;
        for (int bb = T_STEPS - 1; bb >= 0; --bb) { offs[bb] = acc; acc += hist[bb]; }
    }
    __syncthreads();
    if (tid < T_STEPS) cur[tid] = offs[tid];
    __syncthreads();
    for (int i = tid; i < N; i += PREP_THREADS) {
        int len = xn[i * 4 + 3];
        len = min(max(len, 1), T_STEPS);
        int pos = atomicAdd(&cur[len - 1], 1);
        list[pos] = i;
    }
}

// Persistent blocks (grid=256, 1/CU), dynamic chunk stealing (LPT: chunks are
// desc-length-sorted, atomic counter hands out longest first).
// Per chunk: 8 waves x 64 seqs. Wave w owns units [w*16,(w+1)*16) x 4 gates.
// mfma_f32_16x16x32_bf16: A: lane holds row (l&15), k-octet (l>>4)*8.
//                         B: lane holds col (l&15), k-octet (l>>4)*8.
//                         D: lane holds n=(l&15), m=(l>>4)*4+reg  [m89 verified].
// Lane-local LSTM cell math; xw via non-temporal loads (keep W L2-resident).
__global__ __launch_bounds__(NTHREADS)
void lstm_main(const float* __restrict__ xw, const int* __restrict__ xn,
               const unsigned short* __restrict__ Whi, const unsigned short* __restrict__ Wlo,
               const float* __restrict__ bsum, const int* __restrict__ list,
               int N, int* __restrict__ ctr, float* __restrict__ out)
{
    __shared__ unsigned short xh_hi[MSEQ][LDK];
    __shared__ unsigned short xh_lo[MSEQ][LDK];
    __shared__ int s_seq[MSEQ];
    __shared__ int s_len[MSEQ];
    __shared__ int s_chunk;

    const int tid = threadIdx.x;
    const int wv = tid >> 6;
    const int lane = tid & 63;
    const int lr = lane & 15;
    const int lh = lane >> 4;
    const int unit = (wv << 4) + lr;
    const int nchunks = (N + MSEQ - 1) / MSEQ;

    // chunk-invariant: per-lane bias, W base pointers
    float bias[4];
#pragma unroll
    for (int g = 0; g < 4; ++g) bias[g] = bsum[(wv << 6) + (g << 4) + lr];
    const unsigned short* __restrict__ wbase_h = Whi + (size_t)(wv << 6) * DIM_K + (lh << 3);
    const unsigned short* __restrict__ wbase_l = Wlo + (size_t)(wv << 6) * DIM_K + (lh << 3);

    // x staging role: thread -> (seq tid>>3, k-octet (tid&7)*8)
    const int xsl = tid >> 3;
    const int xko = (tid & 7) << 3;

    while (true) {
        if (tid == 0) s_chunk = atomicAdd(ctr, 1);
        __syncthreads();                       // also: all waves done with prev chunk
        const int chunk = s_chunk;
        if (chunk >= nchunks) break;           // uniform exit

        // per-chunk init: seq ids, lens, zero h region
        if (tid < MSEQ) {
            int idx = chunk * MSEQ + tid;
            int seq = (idx < N) ? list[idx] : -1;
            s_seq[tid] = seq;
            int len = 0;
            if (seq >= 0) { len = xn[seq * 4 + 3]; len = min(max(len, 1), T_STEPS); }
            s_len[tid] = len;
        }
#pragma unroll
        for (int m = 0; m < 4; ++m)
#pragma unroll
            for (int j = 0; j < 4; ++j) {
                int s = (m << 4) + (lh << 2) + j;
                xh_hi[s][DIM_X + unit] = 0;
                xh_lo[s][DIM_X + unit] = 0;
            }
        __syncthreads();

        // list is desc-sorted -> first seq of chunk has the chunk's max len
        const int maxlen = s_len[0];
        int lenv[4][4];
#pragma unroll
        for (int m = 0; m < 4; ++m)
#pragma unroll
            for (int j = 0; j < 4; ++j) lenv[m][j] = s_len[(m << 4) + (lh << 2) + j];

        float c[4][4];
#pragma unroll
        for (int m = 0; m < 4; ++m)
#pragma unroll
            for (int j = 0; j < 4; ++j) c[m][j] = 0.0f;

        const long xseq = (long)max(s_seq[xsl], 0);

        // stage x(0) via non-temporal loads (don't pollute L2; W must stay resident)
        {
            const float* xp = xw + ((size_t)xseq * T_STEPS + 0) * DIM_X + xko;
            f32x4 a = __builtin_nontemporal_load((const f32x4*)xp);
            f32x4 bq = __builtin_nontemporal_load((const f32x4*)(xp + 4));
            float xv[8] = {a[0], a[1], a[2], a[3], bq[0], bq[1], bq[2], bq[3]};
            bf16x8 hv, lv;
#pragma unroll
            for (int e = 0; e < 8; ++e) {
                unsigned short h = bf16_rn(xv[e]);
                hv[e] = (short)h;
                lv[e] = (short)bf16_rn(xv[e] - bf16_to_f(h));
            }
            *(bf16x8*)&xh_hi[xsl][xko] = hv;
            *(bf16x8*)&xh_lo[xsl][xko] = lv;
        }

        for (int t = 0; t < maxlen; ++t) {
            __syncthreads();   // x(t) + h(t-1) staged

            f32x4 acc[4][4];
#pragma unroll
            for (int m = 0; m < 4; ++m)
#pragma unroll
                for (int g = 0; g < 4; ++g)
                    acc[m][g] = (f32x4){bias[g], bias[g], bias[g], bias[g]};

            for (int kc = 0; kc < 6; ++kc) {
                const int kb = kc << 5;           // k base (elements)
                bf16x8 ahi[4], alo[4];
#pragma unroll
                for (int m = 0; m < 4; ++m) {
                    ahi[m] = *(const bf16x8*)&xh_hi[(m << 4) + lr][kb + (lh << 3)];
                    alo[m] = *(const bf16x8*)&xh_lo[(m << 4) + lr][kb + (lh << 3)];
                }
                bf16x8 bhi[4], blo[4];
#pragma unroll
                for (int g = 0; g < 4; ++g) {
                    const size_t off = (size_t)((g << 4) + lr) * DIM_K + kb;
                    bhi[g] = *(const bf16x8*)(wbase_h + off);
                    blo[g] = *(const bf16x8*)(wbase_l + off);
                }
#pragma unroll
                for (int m = 0; m < 4; ++m)
#pragma unroll
                    for (int g = 0; g < 4; ++g) {
                        acc[m][g] = __builtin_amdgcn_mfma_f32_16x16x32_bf16(ahi[m], bhi[g], acc[m][g], 0, 0, 0);
                        acc[m][g] = __builtin_amdgcn_mfma_f32_16x16x32_bf16(alo[m], bhi[g], acc[m][g], 0, 0, 0);
                        acc[m][g] = __builtin_amdgcn_mfma_f32_16x16x32_bf16(ahi[m], blo[g], acc[m][g], 0, 0, 0);
                    }
            }

            // prefetch x(t+1) into registers (nt: bypass L2)
            const bool do_x = (t + 1 < maxlen);
            f32x4 xa, xb;
            if (do_x) {
                const float* xp = xw + ((size_t)xseq * T_STEPS + (t + 1)) * DIM_X + xko;
                xa = __builtin_nontemporal_load((const f32x4*)xp);
                xb = __builtin_nontemporal_load((const f32x4*)(xp + 4));
            }

            __syncthreads();   // all LDS reads of step t done

            if (do_x) {
                float xv[8] = {xa[0], xa[1], xa[2], xa[3], xb[0], xb[1], xb[2], xb[3]};
                bf16x8 hv, lv;
#pragma unroll
                for (int e = 0; e < 8; ++e) {
                    unsigned short h = bf16_rn(xv[e]);
                    hv[e] = (short)h;
                    lv[e] = (short)bf16_rn(xv[e] - bf16_to_f(h));
                }
                *(bf16x8*)&xh_hi[xsl][xko] = hv;
                *(bf16x8*)&xh_lo[xsl][xko] = lv;
            }

#pragma unroll
            for (int m = 0; m < 4; ++m)
#pragma unroll
                for (int j = 0; j < 4; ++j) {
                    float iv = fsigmoid(acc[m][0][j]);
                    float fv = fsigmoid(acc[m][1][j]);
                    float gv = ftanh_(acc[m][2][j]);
                    float ov = fsigmoid(acc[m][3][j]);
                    float cv = fv * c[m][j] + iv * gv;
                    c[m][j] = cv;
                    float hv = ov * ftanh_(cv);
                    int s = (m << 4) + (lh << 2) + j;
                    unsigned short hh = bf16_rn(hv);
                    xh_hi[s][DIM_X + unit] = hh;
                    xh_lo[s][DIM_X + unit] = bf16_rn(hv - bf16_to_f(hh));
                    if (t == lenv[m][j] - 1) {
                        int gs = s_seq[s];
                        if (gs >= 0)
                            __builtin_nontemporal_store(hv, &out[(size_t)gs * DIM_H + unit]);
                    }
                }
        }
    }
}

extern "C" void kernel_launch(void* const* d_in, const int* in_sizes, int n_in,
                              void* d_out, int out_size, void* d_ws, size_t ws_size,
                              hipStream_t stream) {
    const float* xw   = (const float*)d_in[0];
    const int*   xn   = (const int*)d_in[1];
    const float* W_ih = (const float*)d_in[2];
    const float* W_hh = (const float*)d_in[3];
    const float* b_ih = (const float*)d_in[4];
    const float* b_hh = (const float*)d_in[5];
    float* out = (float*)d_out;

    const int N = in_sizes[0] / (T_STEPS * DIM_X);   // bs*sl

    char* ws = (char*)d_ws;
    unsigned short* Whi  = (unsigned short*)ws;                // 196608 B
    unsigned short* Wlo  = (unsigned short*)(ws + 196608);     // 196608 B
    float*          bsum = (float*)(ws + 393216);              // 2048 B
    int*            ctr  = (int*)(ws + 395264);                // 64 B (steal counter)
    int*            list = (int*)(ws + 395328);                // N*4 B

    prep<<<PACK_BLOCKS + 1, PREP_THREADS, 0, stream>>>(W_ih, W_hh, b_ih, b_hh, xn, N,
                                                       Whi, Wlo, bsum, list, ctr);

    const int nchunks = (N + MSEQ - 1) / MSEQ;
    const int nblocks = min(256, nchunks);
    lstm_main<<<nblocks, NTHREADS, 0, stream>>>(xw, xn, Whi, Wlo, bsum, list, N, ctr, out);
}